// Round 2
// baseline (3919.779 us; speedup 1.0000x reference)
//
#include <hip/hip_runtime.h>
#include <hip/hip_bf16.h>
#include <math.h>

// Problem constants (fixed by the reference)
#define TOK   131072L       // B * H * W = 8 * 128 * 128
#define LOG2E 1.4426950408889634f

typedef __hip_bfloat16  bf16;
typedef __hip_bfloat162 bf162;

__device__ __forceinline__ float gelu_f(float v) {
    return 0.5f * v * (1.0f + erff(v * 0.70710678118654752f));
}

// ---------------- LayerNorm over rows of 180, fp32 in -> bf16 out -------------
__global__ __launch_bounds__(256) void ln_kernel(const float* __restrict__ x,
        const float* __restrict__ w, const float* __restrict__ b,
        bf16* __restrict__ out) {
    const int lane = threadIdx.x & 63;
    const long row = ((long)blockIdx.x << 2) + (threadIdx.x >> 6);
    const float* xr = x + row * 180;
    float v0 = xr[lane];
    float v1 = xr[lane + 64];
    float v2 = (lane < 52) ? xr[lane + 128] : 0.0f;
    float s  = v0 + v1 + v2;
    float sq = v0 * v0 + v1 * v1 + v2 * v2;
    #pragma unroll
    for (int off = 32; off > 0; off >>= 1) {
        s  += __shfl_xor(s, off);
        sq += __shfl_xor(sq, off);
    }
    const float mean = s * (1.0f / 180.0f);
    const float var  = sq * (1.0f / 180.0f) - mean * mean;
    const float rs   = rsqrtf(var + 1e-5f);
    bf16* orow = out + row * 180;
    orow[lane]      = __float2bfloat16((v0 - mean) * rs * w[lane]      + b[lane]);
    orow[lane + 64] = __float2bfloat16((v1 - mean) * rs * w[lane + 64] + b[lane + 64]);
    if (lane < 52)
        orow[lane + 128] = __float2bfloat16((v2 - mean) * rs * w[lane + 128] + b[lane + 128]);
}

// ---------------- GEMM: out[M,N] = A_bf16[M,K] @ W_f32[K,N] + bias (+epi) ----
// 64x64 tile, 256 threads, 4x4 accumulators.
// MODE 0: qkv  (scale cols<180 by 30^-0.5), bf16 out
// MODE 1: fc1  (exact GELU), bf16 out
// MODE 2: proj (+ fp32 resid), fp32 out
// MODE 3: fc2  (+ fp32 resid), fp32 out
template<int K, int NCOLS, int MODE>
__global__ __launch_bounds__(256) void gemm_kernel(
        const bf16* __restrict__ A, const float* __restrict__ Wm,
        const float* __restrict__ bias, const float* __restrict__ resid,
        void* __restrict__ outv) {
    __shared__ float As[16][68];   // [k][m], padded
    __shared__ float Bs[16][68];   // [k][n], padded
    const int tid  = threadIdx.x;
    const int tx   = tid & 15;
    const int ty   = tid >> 4;
    const long row0 = (long)blockIdx.x * 64;
    const int col0  = blockIdx.y * 64;
    const int ar = tid >> 2;            // A tile row 0..63
    const int ak = (tid & 3) << 2;      // A tile k  0,4,8,12
    const int bk = tid >> 4;            // B tile k  0..15
    const int bc = (tid & 15) << 2;     // B tile col 0..60
    float acc[4][4] = {};
    for (int k0 = 0; k0 < K; k0 += 16) {
        float4 av = make_float4(0.f, 0.f, 0.f, 0.f);
        if (k0 + ak < K) {  // K,ak multiples of 4 -> in-bounds 4-wide load
            union { short4 s4; bf162 h[2]; } u;
            u.s4 = *(const short4*)(A + (row0 + ar) * K + k0 + ak);
            const float2 f0 = __bfloat1622float2(u.h[0]);
            const float2 f1 = __bfloat1622float2(u.h[1]);
            av = make_float4(f0.x, f0.y, f1.x, f1.y);
        }
        As[ak    ][ar] = av.x;
        As[ak + 1][ar] = av.y;
        As[ak + 2][ar] = av.z;
        As[ak + 3][ar] = av.w;
        float4 bv = make_float4(0.f, 0.f, 0.f, 0.f);
        if (k0 + bk < K && col0 + bc < NCOLS)
            bv = *(const float4*)(Wm + (long)(k0 + bk) * NCOLS + col0 + bc);
        *(float4*)&Bs[bk][bc] = bv;
        __syncthreads();
        #pragma unroll
        for (int k = 0; k < 16; ++k) {
            float a[4], bq[4];
            *(float4*)a  = *(const float4*)&As[k][ty << 2];
            *(float4*)bq = *(const float4*)&Bs[k][tx << 2];
            #pragma unroll
            for (int i = 0; i < 4; ++i)
                #pragma unroll
                for (int j = 0; j < 4; ++j)
                    acc[i][j] += a[i] * bq[j];
        }
        __syncthreads();
    }
    const int cb = col0 + (tx << 2);
    if (cb < NCOLS) {
        #pragma unroll
        for (int i = 0; i < 4; ++i) {
            const long r = row0 + (ty << 2) + i;
            float v[4];
            #pragma unroll
            for (int j = 0; j < 4; ++j) v[j] = acc[i][j] + bias[cb + j];
            if (MODE == 0) {
                if (cb < 180) {   // q columns: scale by hd^-0.5
                    #pragma unroll
                    for (int j = 0; j < 4; ++j) v[j] *= 0.18257418583505536f;
                }
            } else if (MODE == 1) {
                #pragma unroll
                for (int j = 0; j < 4; ++j) v[j] = gelu_f(v[j]);
            } else {
                const float4 rv = *(const float4*)(resid + r * NCOLS + cb);
                v[0] += rv.x; v[1] += rv.y; v[2] += rv.z; v[3] += rv.w;
            }
            if (MODE == 0 || MODE == 1) {
                union { short4 s4; bf16 h[4]; } ou;
                #pragma unroll
                for (int j = 0; j < 4; ++j) ou.h[j] = __float2bfloat16(v[j]);
                *(short4*)((bf16*)outv + r * NCOLS + cb) = ou.s4;
            } else {
                *(float4*)((float*)outv + r * NCOLS + cb) = *(float4*)v;
            }
        }
    }
}

// ---------------- transposed relative-position bias table ---------------------
// biasT[h][j][t] = rpb[rpi[t*256+j]*6 + h]  -> coalesced over t in attention
__global__ __launch_bounds__(256) void biast_kernel(const float* __restrict__ rpb,
        const int* __restrict__ rpi, float* __restrict__ biasT) {
    const int idx = blockIdx.x * 256 + threadIdx.x;   // idx = j*256 + t
    const int t  = idx & 255;
    const int jj = idx >> 8;
    const int r = rpi[t * 256 + jj];
    #pragma unroll
    for (int h = 0; h < 6; ++h)
        biasT[h * 65536 + idx] = rpb[r * 6 + h];
}

// ---------------- windowed attention: one block per (window, head) ------------
// 128 threads, 2 query rows each. k/v staged in LDS (bf16). Online softmax.
// Gathers q/k/v rows from token-order qkv via the shift map and scatters the
// output back to token order (the shift map is its own inverse here).
__global__ __launch_bounds__(128) void attn_kernel(
        const bf16* __restrict__ qkv, const float* __restrict__ biasT,
        bf16* __restrict__ attn_out) {
    __shared__ bf162 kp[256][16];   // 256 keys x 32 bf16 (30 used)
    __shared__ bf162 vp[256][16];
    __shared__ int regid[256];

    const int whid = blockIdx.x;
    const int win  = whid / 6;
    const int head = whid - win * 6;
    const int bimg = win >> 6;
    const int wi   = win & 63;
    const int whr  = wi >> 3, wwc = wi & 7;
    const int tid  = threadIdx.x;

    long g[2];
    int  rt[2];
    float q[2][30];

    #pragma unroll
    for (int s = 0; s < 2; ++s) {
        const int rr = tid + s * 128;
        const int i  = rr >> 4, jj = rr & 15;
        const int p  = whr * 16 + i;      // rolled-image coords (== mask coords)
        const int qq = wwc * 16 + jj;
        const int hr = (p + 8) & 127;     // inverse shift -> source token
        const int wc = (qq + 8) & 127;
        const long gr = (long)bimg * 16384 + hr * 128 + wc;
        g[s] = gr;
        const int rh = (p  < 112) ? 0 : ((p  < 120) ? 1 : 2);
        const int rw = (qq < 112) ? 0 : ((qq < 120) ? 1 : 2);
        const int rid = rh * 3 + rw;
        rt[s] = rid;
        regid[rr] = rid;
        const bf162* base2 = (const bf162*)(qkv + gr * 540 + head * 30);
        #pragma unroll
        for (int pp = 0; pp < 15; ++pp) {
            const float2 qf = __bfloat1622float2(base2[pp]);
            q[s][2 * pp]     = qf.x;
            q[s][2 * pp + 1] = qf.y;
            kp[rr][pp] = base2[90 + pp];    // k at bf16 offset 180
            vp[rr][pp] = base2[180 + pp];   // v at bf16 offset 360
        }
    }
    __syncthreads();

    float m[2] = {-1e30f, -1e30f};
    float l[2] = {0.f, 0.f};
    float acc[2][30] = {};
    const float* bptr = biasT + head * 65536 + tid;

    for (int j = 0; j < 256; ++j) {
        float s0 = 0.f, s1 = 0.f;
        #pragma unroll
        for (int pp = 0; pp < 15; ++pp) {
            const float2 kf = __bfloat1622float2(kp[j][pp]);
            s0 += q[0][2*pp] * kf.x + q[0][2*pp+1] * kf.y;
            s1 += q[1][2*pp] * kf.x + q[1][2*pp+1] * kf.y;
        }
        const int rj = regid[j];
        s0 += bptr[j * 256]       + ((rt[0] == rj) ? 0.f : -100.f);
        s1 += bptr[j * 256 + 128] + ((rt[1] == rj) ? 0.f : -100.f);

        if (s0 > m[0]) {  // rare rescale
            const float al = __builtin_amdgcn_exp2f((m[0] - s0) * LOG2E);
            l[0] *= al;
            #pragma unroll
            for (int d = 0; d < 30; ++d) acc[0][d] *= al;
            m[0] = s0;
        }
        const float p0 = __builtin_amdgcn_exp2f((s0 - m[0]) * LOG2E);
        l[0] += p0;
        if (s1 > m[1]) {
            const float al = __builtin_amdgcn_exp2f((m[1] - s1) * LOG2E);
            l[1] *= al;
            #pragma unroll
            for (int d = 0; d < 30; ++d) acc[1][d] *= al;
            m[1] = s1;
        }
        const float p1 = __builtin_amdgcn_exp2f((s1 - m[1]) * LOG2E);
        l[1] += p1;

        #pragma unroll
        for (int pp = 0; pp < 15; ++pp) {
            const float2 vf = __bfloat1622float2(vp[j][pp]);
            acc[0][2*pp]   += p0 * vf.x;
            acc[0][2*pp+1] += p0 * vf.y;
            acc[1][2*pp]   += p1 * vf.x;
            acc[1][2*pp+1] += p1 * vf.y;
        }
    }

    #pragma unroll
    for (int s = 0; s < 2; ++s) {
        const float inv = 1.0f / l[s];
        bf162* op = (bf162*)(attn_out + g[s] * 180 + head * 30);
        #pragma unroll
        for (int pp = 0; pp < 15; ++pp) {
            bf162 o;
            o.x = __float2bfloat16(acc[s][2*pp]   * inv);
            o.y = __float2bfloat16(acc[s][2*pp+1] * inv);
            op[pp] = o;
        }
    }
}

// ---------------- depthwise 5x5 conv + GELU + residual (z = y + gelu(conv)) ---
__global__ __launch_bounds__(256) void dwconv_kernel(const bf16* __restrict__ y,
        const float* __restrict__ dww, const float* __restrict__ dwb,
        bf16* __restrict__ z) {
    const long idx = (long)blockIdx.x * 256 + threadIdx.x;  // ch-fastest, TOK*360
    const int ch = (int)(idx % 360);
    const long t = idx / 360;
    const int pw = (int)(t & 127);
    const int ph = (int)((t >> 7) & 127);
    const int bimg = (int)(t >> 14);
    float s = dwb[ch];
    const float* wp = dww + ch * 25;
    #pragma unroll
    for (int dy = -2; dy <= 2; ++dy) {
        const int hy = ph + dy;
        if (hy < 0 || hy > 127) continue;
        #pragma unroll
        for (int dx = -2; dx <= 2; ++dx) {
            const int wx = pw + dx;
            if (wx < 0 || wx > 127) continue;
            s += __bfloat162float(y[((long)((bimg << 14) + (hy << 7) + wx)) * 360 + ch])
                 * wp[(dy + 2) * 5 + (dx + 2)];
        }
    }
    z[idx] = __float2bfloat16(__bfloat162float(y[idx]) + gelu_f(s));
}

// ---------------- launch --------------------------------------------------------
extern "C" void kernel_launch(void* const* d_in, const int* in_sizes, int n_in,
                              void* d_out, int out_size, void* d_ws, size_t ws_size,
                              hipStream_t stream) {
    const float* x    = (const float*)d_in[0];
    // d_in[1] = attn_mask: unused (mask recomputed analytically in-kernel)
    const int*   rpi  = (const int*)d_in[2];
    const float* n1w  = (const float*)d_in[3];
    const float* n1b  = (const float*)d_in[4];
    const float* wqkv = (const float*)d_in[5];
    const float* bqkv = (const float*)d_in[6];
    const float* rpb  = (const float*)d_in[7];
    const float* pw   = (const float*)d_in[8];
    const float* pb   = (const float*)d_in[9];
    const float* n2w  = (const float*)d_in[10];
    const float* n2b  = (const float*)d_in[11];
    const float* f1w  = (const float*)d_in[12];
    const float* f1b  = (const float*)d_in[13];
    const float* dww  = (const float*)d_in[14];
    const float* dwb  = (const float*)d_in[15];
    const float* f2w  = (const float*)d_in[16];
    const float* f2b  = (const float*)d_in[17];
    float* out = (float*)d_out;

    // workspace layout (bytes):
    //   [0, 141,557,760)              qkvb: 540*TOK bf16   (later: y = first 360*TOK,
    //                                                        z = [360*TOK, 720*TOK) spills into abuf)
    //   [141,557,760, 188,743,680)    abuf: 180*TOK bf16   (xn1 / attn_out / xn2; dead when z written)
    //   [188,743,680, 190,316,544)    bT:   393,216 f32
    // x2 (fp32 post-attn residual) lives in d_out itself.
    const size_t NEED = 540L * TOK * 2 + 180L * TOK * 2 + 393216L * 4;
    if (ws_size < NEED) return;   // fail visibly (absmax) instead of faulting

    bf16* qkvb = (bf16*)d_ws;
    bf16* abuf = qkvb + 540L * TOK;
    bf16* ybuf = qkvb;                    // alias: qkv dead after attention
    bf16* zbuf = qkvb + 360L * TOK;       // spans qkvb tail + abuf (both dead)
    float* bT  = (float*)(qkvb + 720L * TOK);

    biast_kernel<<<256, 256, 0, stream>>>(rpb, rpi, bT);
    ln_kernel<<<32768, 256, 0, stream>>>(x, n1w, n1b, abuf);
    gemm_kernel<180, 540, 0><<<dim3(2048, 9), 256, 0, stream>>>(abuf, wqkv, bqkv, nullptr, qkvb);
    attn_kernel<<<3072, 128, 0, stream>>>(qkvb, bT, abuf);          // abuf := attn_out
    gemm_kernel<180, 180, 2><<<dim3(2048, 3), 256, 0, stream>>>(abuf, pw, pb, x, out);  // out := x2
    ln_kernel<<<32768, 256, 0, stream>>>(out, n2w, n2b, abuf);      // abuf := xn2
    gemm_kernel<180, 360, 1><<<dim3(2048, 6), 256, 0, stream>>>(abuf, f1w, f1b, nullptr, ybuf);
    dwconv_kernel<<<184320, 256, 0, stream>>>(ybuf, dww, dwb, zbuf);
    gemm_kernel<360, 180, 3><<<dim3(2048, 3), 256, 0, stream>>>(zbuf, f2w, f2b, out, out);
}

// Round 3
// 2732.060 us; speedup vs baseline: 1.4347x; 1.4347x over previous
//
#include <hip/hip_runtime.h>
#include <hip/hip_bf16.h>
#include <math.h>

// Problem constants (fixed by the reference)
#define TOK   131072L       // B * H * W = 8 * 128 * 128
#define LOG2E 1.4426950408889634f

typedef __hip_bfloat16  bf16;
typedef __hip_bfloat162 bf162;
typedef __attribute__((ext_vector_type(8))) short  bf16x8;   // MFMA A/B frag (4 VGPR)
typedef __attribute__((ext_vector_type(4))) float  f32x4;    // MFMA C/D frag

__device__ __forceinline__ float gelu_f(float v) {
    return 0.5f * v * (1.0f + erff(v * 0.70710678118654752f));
}
__device__ __forceinline__ short bf16bits(float v) {
    union { bf16 h; short s; } u; u.h = __float2bfloat16(v); return u.s;
}

// ---------------- LayerNorm over rows of 180, fp32 in -> bf16 out -------------
__global__ __launch_bounds__(256) void ln_kernel(const float* __restrict__ x,
        const float* __restrict__ w, const float* __restrict__ b,
        bf16* __restrict__ out) {
    const int lane = threadIdx.x & 63;
    const long row = ((long)blockIdx.x << 2) + (threadIdx.x >> 6);
    const float* xr = x + row * 180;
    float v0 = xr[lane];
    float v1 = xr[lane + 64];
    float v2 = (lane < 52) ? xr[lane + 128] : 0.0f;
    float s  = v0 + v1 + v2;
    float sq = v0 * v0 + v1 * v1 + v2 * v2;
    #pragma unroll
    for (int off = 32; off > 0; off >>= 1) {
        s  += __shfl_xor(s, off);
        sq += __shfl_xor(sq, off);
    }
    const float mean = s * (1.0f / 180.0f);
    const float var  = sq * (1.0f / 180.0f) - mean * mean;
    const float rs   = rsqrtf(var + 1e-5f);
    bf16* orow = out + row * 180;
    orow[lane]      = __float2bfloat16((v0 - mean) * rs * w[lane]      + b[lane]);
    orow[lane + 64] = __float2bfloat16((v1 - mean) * rs * w[lane + 64] + b[lane + 64]);
    if (lane < 52)
        orow[lane + 128] = __float2bfloat16((v2 - mean) * rs * w[lane + 128] + b[lane + 128]);
}

// ---------------- MFMA GEMM: out[M,N] = A_bf16[M,K] @ W_f32[K,N] + bias -------
// Block: 256 threads (4 waves), 64x64 output tile. K staged in chunks of <=192.
// Wave w computes rows [w*16, w*16+16) x all 64 cols (4 n-tiles of 16).
// mfma_f32_16x16x32_bf16 with roles swapped: a_frag <- W^T tile, b_frag <- X^T,
// so D[m][n] = out[row0 + w*16 + n][col0 + t*16 + m]  (m = quad*4+reg, n = lane&15).
// MODE 0: qkv  (scale cols<180 by 30^-0.5), bf16 out
// MODE 1: fc1  (exact GELU), bf16 out
// MODE 2: proj (+ fp32 resid), fp32 out
// MODE 3: fc2  (+ fp32 resid), fp32 out
template<int K, int NCOLS, int MODE>
__global__ __launch_bounds__(256) void gemm_mfma(
        const bf16* __restrict__ A, const float* __restrict__ Wm,
        const float* __restrict__ bias, const float* __restrict__ resid,
        void* __restrict__ outv) {
    // LDS: row stride 200 bf16 (400 B, 100 dwords -> conflict-free b128 frags)
    __shared__ short xs [64 * 200];   // X^T panel:  xs[r][k]  = X[row0+r][kb+k]
    __shared__ short wsm[64 * 200];   // W^T panel: wsm[n][k]  = W[kb+k][col0+n]
    const int tid  = threadIdx.x;
    const int wave = tid >> 6;
    const int lane = tid & 63;
    const int n15  = lane & 15;
    const int quad = lane >> 4;
    const long row0 = (long)blockIdx.x * 64;
    const int  col0 = blockIdx.y * 64;
    constexpr int NCH = (K + 191) / 192;

    f32x4 acc[4] = {};   // 4 n-tiles of 16 cols

    #pragma unroll
    for (int c = 0; c < NCH; ++c) {
        const int kb = c * 192;
        if (c > 0) __syncthreads();   // waves done with prev chunk's LDS
        // --- stage X: 4 threads per row, 48 bf16 each (short4 = 8B aligned) ---
        {
            const int r  = tid >> 2;
            const int kt = (tid & 3) * 48;
            const bf16* arow = A + (row0 + r) * K;
            #pragma unroll
            for (int i = 0; i < 48; i += 4) {
                const int k = kb + kt + i;
                short4 v = make_short4(0, 0, 0, 0);
                if (k + 4 <= K) v = *(const short4*)(arow + k);
                *(short4*)(xs + r * 200 + kt + i) = v;
            }
        }
        // --- stage W (fp32 -> bf16, transposed): lane n = col, 48 k each ------
        {
            const int n   = tid & 63;
            const int kt0 = (tid >> 6) * 48;
            const int col = col0 + n;
            const bool cok = (col < NCOLS);
            #pragma unroll
            for (int i = 0; i < 48; ++i) {
                const int k = kb + kt0 + i;
                float wv = (cok && k < K) ? Wm[(long)k * NCOLS + col] : 0.0f;
                wsm[n * 200 + kt0 + i] = bf16bits(wv);
            }
        }
        __syncthreads();
        // --- 6 MFMA k-steps over the 192-wide chunk ---------------------------
        #pragma unroll
        for (int s = 0; s < 6; ++s) {
            const int k0 = s * 32;
            const bf16x8 bfrag = *(const bf16x8*)(xs + (wave * 16 + n15) * 200 + k0 + quad * 8);
            #pragma unroll
            for (int t = 0; t < 4; ++t) {
                const bf16x8 afrag = *(const bf16x8*)(wsm + (t * 16 + n15) * 200 + k0 + quad * 8);
                acc[t] = __builtin_amdgcn_mfma_f32_16x16x32_bf16(afrag, bfrag, acc[t], 0, 0, 0);
            }
        }
    }

    // --- epilogue: transpose through LDS for coalesced stores -----------------
    __syncthreads();                 // all frag reads done; xs reusable
    float* Cs = (float*)xs;          // Cs[64][68]: 17408 f32 <= xs capacity
    #pragma unroll
    for (int t = 0; t < 4; ++t)
        #pragma unroll
        for (int r = 0; r < 4; ++r)
            Cs[(wave * 16 + n15) * 68 + t * 16 + quad * 4 + r] = acc[t][r];
    __syncthreads();

    const int  rr   = tid >> 2;        // 0..63 local row
    const int  c16  = (tid & 3) * 16;  // 16-col segment
    const long grow = row0 + rr;
    #pragma unroll
    for (int j4 = 0; j4 < 4; ++j4) {
        const int col4 = col0 + c16 + j4 * 4;
        if (col4 >= NCOLS) continue;   // NCOLS % 4 == 0 -> chunk all-in or all-out
        float v[4];
        *(f32x4*)v = *(const f32x4*)(Cs + rr * 68 + c16 + j4 * 4);
        #pragma unroll
        for (int j = 0; j < 4; ++j) v[j] += bias[col4 + j];
        if (MODE == 0) {
            if (col4 < 180) {
                #pragma unroll
                for (int j = 0; j < 4; ++j) v[j] *= 0.18257418583505536f;
            }
        } else if (MODE == 1) {
            #pragma unroll
            for (int j = 0; j < 4; ++j) v[j] = gelu_f(v[j]);
        } else {
            const float4 rv = *(const float4*)(resid + grow * NCOLS + col4);
            v[0] += rv.x; v[1] += rv.y; v[2] += rv.z; v[3] += rv.w;
        }
        if (MODE == 0 || MODE == 1) {
            short4 ou;
            ou.x = bf16bits(v[0]); ou.y = bf16bits(v[1]);
            ou.z = bf16bits(v[2]); ou.w = bf16bits(v[3]);
            *(short4*)((bf16*)outv + grow * NCOLS + col4) = ou;
        } else {
            *(float4*)((float*)outv + grow * NCOLS + col4) = *(float4*)v;
        }
    }
}

// ---------------- transposed relative-position bias table ---------------------
__global__ __launch_bounds__(256) void biast_kernel(const float* __restrict__ rpb,
        const int* __restrict__ rpi, float* __restrict__ biasT) {
    const int idx = blockIdx.x * 256 + threadIdx.x;   // idx = j*256 + t
    const int t  = idx & 255;
    const int jj = idx >> 8;
    const int r = rpi[t * 256 + jj];
    #pragma unroll
    for (int h = 0; h < 6; ++h)
        biasT[h * 65536 + idx] = rpb[r * 6 + h];
}

// ---------------- windowed attention: one block per (window, head) ------------
__global__ __launch_bounds__(128) void attn_kernel(
        const bf16* __restrict__ qkv, const float* __restrict__ biasT,
        bf16* __restrict__ attn_out) {
    __shared__ bf162 kp[256][16];   // 256 keys x 32 bf16 (30 used)
    __shared__ bf162 vp[256][16];
    __shared__ int regid[256];

    const int whid = blockIdx.x;
    const int win  = whid / 6;
    const int head = whid - win * 6;
    const int bimg = win >> 6;
    const int wi   = win & 63;
    const int whr  = wi >> 3, wwc = wi & 7;
    const int tid  = threadIdx.x;

    long g[2];
    int  rt[2];
    float q[2][30];

    #pragma unroll
    for (int s = 0; s < 2; ++s) {
        const int rr = tid + s * 128;
        const int i  = rr >> 4, jj = rr & 15;
        const int p  = whr * 16 + i;      // rolled-image coords (== mask coords)
        const int qq = wwc * 16 + jj;
        const int hr = (p + 8) & 127;     // inverse shift -> source token
        const int wc = (qq + 8) & 127;
        const long gr = (long)bimg * 16384 + hr * 128 + wc;
        g[s] = gr;
        const int rh = (p  < 112) ? 0 : ((p  < 120) ? 1 : 2);
        const int rw = (qq < 112) ? 0 : ((qq < 120) ? 1 : 2);
        const int rid = rh * 3 + rw;
        rt[s] = rid;
        regid[rr] = rid;
        const bf162* base2 = (const bf162*)(qkv + gr * 540 + head * 30);
        #pragma unroll
        for (int pp = 0; pp < 15; ++pp) {
            const float2 qf = __bfloat1622float2(base2[pp]);
            q[s][2 * pp]     = qf.x;
            q[s][2 * pp + 1] = qf.y;
            kp[rr][pp] = base2[90 + pp];    // k at bf16 offset 180
            vp[rr][pp] = base2[180 + pp];   // v at bf16 offset 360
        }
    }
    __syncthreads();

    float m[2] = {-1e30f, -1e30f};
    float l[2] = {0.f, 0.f};
    float acc[2][30] = {};
    const float* bptr = biasT + head * 65536 + tid;

    for (int j = 0; j < 256; ++j) {
        float s0 = 0.f, s1 = 0.f;
        #pragma unroll
        for (int pp = 0; pp < 15; ++pp) {
            const float2 kf = __bfloat1622float2(kp[j][pp]);
            s0 += q[0][2*pp] * kf.x + q[0][2*pp+1] * kf.y;
            s1 += q[1][2*pp] * kf.x + q[1][2*pp+1] * kf.y;
        }
        const int rj = regid[j];
        s0 += bptr[j * 256]       + ((rt[0] == rj) ? 0.f : -100.f);
        s1 += bptr[j * 256 + 128] + ((rt[1] == rj) ? 0.f : -100.f);

        if (s0 > m[0]) {  // rare rescale
            const float al = __builtin_amdgcn_exp2f((m[0] - s0) * LOG2E);
            l[0] *= al;
            #pragma unroll
            for (int d = 0; d < 30; ++d) acc[0][d] *= al;
            m[0] = s0;
        }
        const float p0 = __builtin_amdgcn_exp2f((s0 - m[0]) * LOG2E);
        l[0] += p0;
        if (s1 > m[1]) {
            const float al = __builtin_amdgcn_exp2f((m[1] - s1) * LOG2E);
            l[1] *= al;
            #pragma unroll
            for (int d = 0; d < 30; ++d) acc[1][d] *= al;
            m[1] = s1;
        }
        const float p1 = __builtin_amdgcn_exp2f((s1 - m[1]) * LOG2E);
        l[1] += p1;

        #pragma unroll
        for (int pp = 0; pp < 15; ++pp) {
            const float2 vf = __bfloat1622float2(vp[j][pp]);
            acc[0][2*pp]   += p0 * vf.x;
            acc[0][2*pp+1] += p0 * vf.y;
            acc[1][2*pp]   += p1 * vf.x;
            acc[1][2*pp+1] += p1 * vf.y;
        }
    }

    #pragma unroll
    for (int s = 0; s < 2; ++s) {
        const float inv = 1.0f / l[s];
        bf162* op = (bf162*)(attn_out + g[s] * 180 + head * 30);
        #pragma unroll
        for (int pp = 0; pp < 15; ++pp) {
            bf162 o;
            o.x = __float2bfloat16(acc[s][2*pp]   * inv);
            o.y = __float2bfloat16(acc[s][2*pp+1] * inv);
            op[pp] = o;
        }
    }
}

// ---------------- depthwise 5x5 conv + GELU + residual (z = y + gelu(conv)) ---
// Block: 64 tokens x 180 channel-pairs; weights staged in LDS [tap][ch].
__global__ __launch_bounds__(256) void dwconv_kernel(const bf16* __restrict__ y,
        const float* __restrict__ dww, const float* __restrict__ dwb,
        bf16* __restrict__ z) {
    __shared__ float wl[25 * 360];   // [tap][ch], 36 KB
    __shared__ float bl[360];
    const int tid = threadIdx.x;
    for (int e = tid; e < 9000; e += 256) {
        const int ch = e / 25;
        const int tap = e - ch * 25;
        wl[tap * 360 + ch] = dww[e];
    }
    for (int e = tid; e < 360; e += 256) bl[e] = dwb[e];
    __syncthreads();

    const bf162* y2 = (const bf162*)y;
    bf162* z2 = (bf162*)z;
    const int base_t = blockIdx.x * 64;

    #pragma unroll 1
    for (int it = 0; it < 45; ++it) {
        const int item = it * 256 + tid;          // 0..11519
        const int tl = item / 180;                // token local (0..63)
        const int pr = item - tl * 180;           // channel pair (0..179)
        const int t  = base_t + tl;
        const int pw_  = t & 127;
        const int ph   = (t >> 7) & 127;
        const int bimg = t >> 14;
        float s0 = bl[2 * pr], s1 = bl[2 * pr + 1];
        #pragma unroll
        for (int dy = -2; dy <= 2; ++dy) {
            const int hy = ph + dy;
            if (hy < 0 || hy > 127) continue;
            #pragma unroll
            for (int dx = -2; dx <= 2; ++dx) {
                const int wx = pw_ + dx;
                if (wx < 0 || wx > 127) continue;
                const float2 wv = *(const float2*)(wl + ((dy + 2) * 5 + (dx + 2)) * 360 + 2 * pr);
                const float2 yf = __bfloat1622float2(
                    y2[(long)((bimg << 14) + (hy << 7) + wx) * 180 + pr]);
                s0 += yf.x * wv.x;
                s1 += yf.y * wv.y;
            }
        }
        const long oidx = (long)t * 180 + pr;
        const float2 yr = __bfloat1622float2(y2[oidx]);
        bf162 o;
        o.x = __float2bfloat16(yr.x + gelu_f(s0));
        o.y = __float2bfloat16(yr.y + gelu_f(s1));
        z2[oidx] = o;
    }
}

// ---------------- launch --------------------------------------------------------
extern "C" void kernel_launch(void* const* d_in, const int* in_sizes, int n_in,
                              void* d_out, int out_size, void* d_ws, size_t ws_size,
                              hipStream_t stream) {
    const float* x    = (const float*)d_in[0];
    // d_in[1] = attn_mask: unused (mask recomputed analytically in-kernel)
    const int*   rpi  = (const int*)d_in[2];
    const float* n1w  = (const float*)d_in[3];
    const float* n1b  = (const float*)d_in[4];
    const float* wqkv = (const float*)d_in[5];
    const float* bqkv = (const float*)d_in[6];
    const float* rpb  = (const float*)d_in[7];
    const float* pw   = (const float*)d_in[8];
    const float* pb   = (const float*)d_in[9];
    const float* n2w  = (const float*)d_in[10];
    const float* n2b  = (const float*)d_in[11];
    const float* f1w  = (const float*)d_in[12];
    const float* f1b  = (const float*)d_in[13];
    const float* dww  = (const float*)d_in[14];
    const float* dwb  = (const float*)d_in[15];
    const float* f2w  = (const float*)d_in[16];
    const float* f2b  = (const float*)d_in[17];
    float* out = (float*)d_out;

    // workspace layout (see round-1 notes): 190 MB total
    const size_t NEED = 540L * TOK * 2 + 180L * TOK * 2 + 393216L * 4;
    if (ws_size < NEED) return;

    bf16* qkvb = (bf16*)d_ws;
    bf16* abuf = qkvb + 540L * TOK;
    bf16* ybuf = qkvb;                    // alias: qkv dead after attention
    bf16* zbuf = qkvb + 360L * TOK;       // spans qkvb tail + abuf (both dead)
    float* bT  = (float*)(qkvb + 720L * TOK);

    biast_kernel<<<256, 256, 0, stream>>>(rpb, rpi, bT);
    ln_kernel<<<32768, 256, 0, stream>>>(x, n1w, n1b, abuf);
    gemm_mfma<180, 540, 0><<<dim3(2048, 9), 256, 0, stream>>>(abuf, wqkv, bqkv, nullptr, qkvb);
    attn_kernel<<<3072, 128, 0, stream>>>(qkvb, bT, abuf);          // abuf := attn_out
    gemm_mfma<180, 180, 2><<<dim3(2048, 3), 256, 0, stream>>>(abuf, pw, pb, x, out);  // out := x2
    ln_kernel<<<32768, 256, 0, stream>>>(out, n2w, n2b, abuf);      // abuf := xn2
    gemm_mfma<180, 360, 1><<<dim3(2048, 6), 256, 0, stream>>>(abuf, f1w, f1b, nullptr, ybuf);
    dwconv_kernel<<<2048, 256, 0, stream>>>(ybuf, dww, dwb, zbuf);
    gemm_mfma<360, 180, 3><<<dim3(2048, 3), 256, 0, stream>>>(zbuf, f2w, f2b, out, out);
}

// Round 4
// 1622.920 us; speedup vs baseline: 2.4153x; 1.6834x over previous
//
#include <hip/hip_runtime.h>
#include <hip/hip_bf16.h>
#include <math.h>

// Problem constants (fixed by the reference)
#define TOK   131072L       // B * H * W = 8 * 128 * 128
#define LOG2E 1.4426950408889634f

typedef __hip_bfloat16  bf16;
typedef __hip_bfloat162 bf162;
typedef __attribute__((ext_vector_type(8))) short  bf16x8;   // MFMA A/B frag (4 VGPR)
typedef __attribute__((ext_vector_type(4))) float  f32x4;    // MFMA C/D frag

__device__ __forceinline__ float gelu_f(float v) {
    return 0.5f * v * (1.0f + erff(v * 0.70710678118654752f));
}
__device__ __forceinline__ short bf16bits(float v) {
    union { bf16 h; short s; } u; u.h = __float2bfloat16(v); return u.s;
}

// ---------------- LayerNorm over rows of 180, fp32 in -> bf16 out -------------
__global__ __launch_bounds__(256) void ln_kernel(const float* __restrict__ x,
        const float* __restrict__ w, const float* __restrict__ b,
        bf16* __restrict__ out) {
    const int lane = threadIdx.x & 63;
    const long row = ((long)blockIdx.x << 2) + (threadIdx.x >> 6);
    const float* xr = x + row * 180;
    float v0 = xr[lane];
    float v1 = xr[lane + 64];
    float v2 = (lane < 52) ? xr[lane + 128] : 0.0f;
    float s  = v0 + v1 + v2;
    float sq = v0 * v0 + v1 * v1 + v2 * v2;
    #pragma unroll
    for (int off = 32; off > 0; off >>= 1) {
        s  += __shfl_xor(s, off);
        sq += __shfl_xor(sq, off);
    }
    const float mean = s * (1.0f / 180.0f);
    const float var  = sq * (1.0f / 180.0f) - mean * mean;
    const float rs   = rsqrtf(var + 1e-5f);
    bf16* orow = out + row * 180;
    orow[lane]      = __float2bfloat16((v0 - mean) * rs * w[lane]      + b[lane]);
    orow[lane + 64] = __float2bfloat16((v1 - mean) * rs * w[lane + 64] + b[lane + 64]);
    if (lane < 52)
        orow[lane + 128] = __float2bfloat16((v2 - mean) * rs * w[lane + 128] + b[lane + 128]);
}

// ---------------- W transpose: fp32 [K][N] -> bf16 [N][K] ---------------------
template<int K, int N>
__global__ __launch_bounds__(256) void wtrans_kernel(const float* __restrict__ W,
        bf16* __restrict__ WT) {
    const int idx = blockIdx.x * 256 + threadIdx.x;
    if (idx >= K * N) return;
    const int k = idx / N, n = idx - k * N;
    WT[n * K + k] = __float2bfloat16(W[idx]);
}

// ---------------- MFMA GEMM: out[M,N] = A_bf16[M,K] @ W + bias (+epi) ---------
// W passed pre-transposed bf16 [N][K]. 64x64 tile, 256 threads, K chunks <=192.
// MODE 0: qkv (scale cols<180), bf16 out | 1: fc1 (GELU), bf16 out
// MODE 2: proj (+f32 resid), f32 out     | 3: fc2 (+f32 resid), f32 out
template<int K, int NCOLS, int MODE>
__global__ __launch_bounds__(256) void gemm_mfma(
        const bf16* __restrict__ A, const bf16* __restrict__ WT,
        const float* __restrict__ bias, const float* __restrict__ resid,
        void* __restrict__ outv) {
    __shared__ short xs [64 * 200];   // X panel:  xs[r][k]
    __shared__ short wsm[64 * 200];   // W panel: wsm[n][k] = W[k][col0+n]
    const int tid  = threadIdx.x;
    const int wave = tid >> 6;
    const int lane = tid & 63;
    const int n15  = lane & 15;
    const int quad = lane >> 4;
    const long row0 = (long)blockIdx.x * 64;
    const int  col0 = blockIdx.y * 64;
    constexpr int NCH = (K + 191) / 192;

    f32x4 acc[4] = {};

    #pragma unroll
    for (int c = 0; c < NCH; ++c) {
        const int kb = c * 192;
        if (c > 0) __syncthreads();
        const int r   = tid >> 2;
        const int seg = (tid & 3) * 48;
        {   // stage X
            const bf16* arow = A + (row0 + r) * K;
            #pragma unroll
            for (int i = 0; i < 48; i += 4) {
                const int k = kb + seg + i;
                short4 v = make_short4(0, 0, 0, 0);
                if (k + 4 <= K) v = *(const short4*)(arow + k);
                *(short4*)(xs + r * 200 + seg + i) = v;
            }
        }
        {   // stage W (bf16, pre-transposed -> vector loads)
            const int col = col0 + r;
            const bf16* wrow = WT + (long)col * K;
            #pragma unroll
            for (int i = 0; i < 48; i += 4) {
                const int k = kb + seg + i;
                short4 v = make_short4(0, 0, 0, 0);
                if (col < NCOLS && k + 4 <= K) v = *(const short4*)(wrow + k);
                *(short4*)(wsm + r * 200 + seg + i) = v;
            }
        }
        __syncthreads();
        #pragma unroll
        for (int s = 0; s < 6; ++s) {
            const int k0 = s * 32;
            const bf16x8 bfrag = *(const bf16x8*)(xs + (wave * 16 + n15) * 200 + k0 + quad * 8);
            #pragma unroll
            for (int t = 0; t < 4; ++t) {
                const bf16x8 afrag = *(const bf16x8*)(wsm + (t * 16 + n15) * 200 + k0 + quad * 8);
                acc[t] = __builtin_amdgcn_mfma_f32_16x16x32_bf16(afrag, bfrag, acc[t], 0, 0, 0);
            }
        }
    }

    // epilogue: transpose through LDS for coalesced stores
    __syncthreads();
    float* Cs = (float*)xs;          // Cs[64][68]
    #pragma unroll
    for (int t = 0; t < 4; ++t)
        #pragma unroll
        for (int r = 0; r < 4; ++r)
            Cs[(wave * 16 + n15) * 68 + t * 16 + quad * 4 + r] = acc[t][r];
    __syncthreads();

    const int  rr   = tid >> 2;
    const int  c16  = (tid & 3) * 16;
    const long grow = row0 + rr;
    #pragma unroll
    for (int j4 = 0; j4 < 4; ++j4) {
        const int col4 = col0 + c16 + j4 * 4;
        if (col4 >= NCOLS) continue;
        float v[4];
        *(f32x4*)v = *(const f32x4*)(Cs + rr * 68 + c16 + j4 * 4);
        #pragma unroll
        for (int j = 0; j < 4; ++j) v[j] += bias[col4 + j];
        if (MODE == 0) {
            if (col4 < 180) {
                #pragma unroll
                for (int j = 0; j < 4; ++j) v[j] *= 0.18257418583505536f;
            }
        } else if (MODE == 1) {
            #pragma unroll
            for (int j = 0; j < 4; ++j) v[j] = gelu_f(v[j]);
        } else {
            const float4 rv = *(const float4*)(resid + grow * NCOLS + col4);
            v[0] += rv.x; v[1] += rv.y; v[2] += rv.z; v[3] += rv.w;
        }
        if (MODE == 0 || MODE == 1) {
            short4 ou;
            ou.x = bf16bits(v[0]); ou.y = bf16bits(v[1]);
            ou.z = bf16bits(v[2]); ou.w = bf16bits(v[3]);
            *(short4*)((bf16*)outv + grow * NCOLS + col4) = ou;
        } else {
            *(float4*)((float*)outv + grow * NCOLS + col4) = *(float4*)v;
        }
    }
}

// ---------------- relative-position bias table, [h][q][k] orientation ---------
__global__ __launch_bounds__(256) void biast_kernel(const float* __restrict__ rpb,
        const int* __restrict__ rpi, float* __restrict__ biasN) {
    const int idx = blockIdx.x * 256 + threadIdx.x;   // idx = q*256 + k
    const int r = rpi[idx];
    #pragma unroll
    for (int h = 0; h < 6; ++h)
        biasN[h * 65536 + idx] = rpb[r * 6 + h];
}

// ---------------- MFMA windowed attention: one block per (window, head) -------
// 4 waves x 64 queries. S via mfma(K_frag, Q_frag) -> D[key][query]; softmax in
// registers (cross-quad shuffles); P -> per-wave LDS (A-layout); PV via
// mfma(P_frag, Vt_frag) -> D[query][dim]. Mask analytic; bias [h][q][k] float4.
#define SK 40    // Ks row stride (bf16): 2-way-free banks, 16B aligned
#define SP 264   // Vt / P row stride (bf16): 2-way-free banks, 16B aligned
__global__ __launch_bounds__(256) void attn_mfma(
        const bf16* __restrict__ qkv, const float* __restrict__ biasN,
        bf16* __restrict__ attn_out) {
    __shared__ short Ks[256 * SK];       // 20480 B [key][dim0..29,pad->0]
    __shared__ short Vt[32 * SP];        // 16896 B [dim][key]
    __shared__ short Pl[4][16 * SP];     // 33792 B per-wave P[q][key]
    __shared__ int   regid[256];
    __shared__ float lsum[4][16];

    const int whid = blockIdx.x;
    const int win  = whid / 6;
    const int head = whid - win * 6;
    const int bimg = win >> 6;
    const int wi   = win & 63;
    const int whr  = wi >> 3, wwc = wi & 7;
    const int tid  = threadIdx.x;

    // ---- stage K (zero-padded dims 30,31) and V^T; region ids ----
    {
        const int t = tid;                      // key 0..255
        const int i = t >> 4, jj = t & 15;
        const int p  = whr * 16 + i;
        const int qq = wwc * 16 + jj;
        const long gr = (long)bimg * 16384 + ((p + 8) & 127) * 128 + ((qq + 8) & 127);
        const int rh = (p  < 112) ? 0 : ((p  < 120) ? 1 : 2);
        const int rw = (qq < 112) ? 0 : ((qq < 120) ? 1 : 2);
        regid[t] = rh * 3 + rw;
        const short2* base2 = (const short2*)(qkv + gr * 540 + head * 30);
        short* krow = Ks + t * SK;
        #pragma unroll
        for (int pp = 0; pp < 15; ++pp) {
            *(short2*)(krow + 2 * pp) = base2[90 + pp];        // k row
            const short2 vv = base2[180 + pp];                 // v dims 2pp,2pp+1
            Vt[(2 * pp)     * SP + t] = vv.x;
            Vt[(2 * pp + 1) * SP + t] = vv.y;
        }
        *(short2*)(krow + 30) = make_short2(0, 0);             // zero pad dims 30,31
        Vt[30 * SP + t] = 0;                                   // keep pad rows finite
        Vt[31 * SP + t] = 0;
    }
    __syncthreads();

    const int wave = tid >> 6, lane = tid & 63;
    const int q15 = lane & 15, quad = lane >> 4;
    const bool boundary = (whr == 7) || (wwc == 7);
    const float* mybias = biasN + head * 65536;
    short* Pw = Pl[wave];

    for (int qt = 0; qt < 4; ++qt) {
        const int qbase = wave * 64 + qt * 16;
        // ---- Q fragment (B-operand): query qbase+q15, dims quad*8..+7 ----
        const int qi = qbase + q15;
        const int pq  = whr * 16 + (qi >> 4);
        const int qqq = wwc * 16 + (qi & 15);
        const long grq = (long)bimg * 16384 + ((pq + 8) & 127) * 128 + ((qqq + 8) & 127);
        union { bf16x8 v; short2 s[4]; } qf;
        const short2* qb = (const short2*)(qkv + grq * 540 + head * 30) + quad * 4;
        #pragma unroll
        for (int j = 0; j < 4; ++j) qf.s[j] = qb[j];

        // ---- S = K·Q^T : 16 key-tiles, D[key=quad*4+r][query=q15] ----
        f32x4 acc[16];
        #pragma unroll
        for (int kt = 0; kt < 16; ++kt) acc[kt] = (f32x4){0.f, 0.f, 0.f, 0.f};
        #pragma unroll
        for (int kt = 0; kt < 16; ++kt) {
            const bf16x8 kfrag = *(const bf16x8*)(Ks + (kt * 16 + q15) * SK + quad * 8);
            acc[kt] = __builtin_amdgcn_mfma_f32_16x16x32_bf16(kfrag, qf.v, acc[kt], 0, 0, 0);
        }

        // ---- softmax over 256 keys (64 in-register + cross-quad shuffles) ----
        const int rtq = ((pq  < 112) ? 0 : ((pq  < 120) ? 1 : 2)) * 3
                      + ((qqq < 112) ? 0 : ((qqq < 120) ? 1 : 2));
        float mx = -1e30f;
        #pragma unroll
        for (int kt = 0; kt < 16; ++kt) {
            const float4 b4 = *(const float4*)(mybias + qi * 256 + kt * 16 + quad * 4);
            float bb[4] = {b4.x, b4.y, b4.z, b4.w};
            if (boundary) {
                const int4 rj = *(const int4*)(regid + kt * 16 + quad * 4);
                bb[0] += (rtq == rj.x) ? 0.f : -100.f;
                bb[1] += (rtq == rj.y) ? 0.f : -100.f;
                bb[2] += (rtq == rj.z) ? 0.f : -100.f;
                bb[3] += (rtq == rj.w) ? 0.f : -100.f;
            }
            #pragma unroll
            for (int r = 0; r < 4; ++r) {
                acc[kt][r] += bb[r];
                mx = fmaxf(mx, acc[kt][r]);
            }
        }
        mx = fmaxf(mx, __shfl_xor(mx, 16));
        mx = fmaxf(mx, __shfl_xor(mx, 32));
        float l = 0.f;
        #pragma unroll
        for (int kt = 0; kt < 16; ++kt) {
            short4 pk;
            float pv0 = __builtin_amdgcn_exp2f((acc[kt][0] - mx) * LOG2E);
            float pv1 = __builtin_amdgcn_exp2f((acc[kt][1] - mx) * LOG2E);
            float pv2 = __builtin_amdgcn_exp2f((acc[kt][2] - mx) * LOG2E);
            float pv3 = __builtin_amdgcn_exp2f((acc[kt][3] - mx) * LOG2E);
            l += pv0 + pv1 + pv2 + pv3;
            pk.x = bf16bits(pv0); pk.y = bf16bits(pv1);
            pk.z = bf16bits(pv2); pk.w = bf16bits(pv3);
            *(short4*)(Pw + q15 * SP + kt * 16 + quad * 4) = pk;
        }
        l += __shfl_xor(l, 16);
        l += __shfl_xor(l, 32);
        if (quad == 0) lsum[wave][q15] = l;
        __syncthreads();   // uniform: all waves execute 4 qt iterations

        // ---- O = P·V : 8 key-chunks x 2 dim-tiles, D[query=quad*4+r][dim=q15] ----
        f32x4 o0 = (f32x4){0.f, 0.f, 0.f, 0.f};
        f32x4 o1 = (f32x4){0.f, 0.f, 0.f, 0.f};
        #pragma unroll
        for (int kc = 0; kc < 8; ++kc) {
            const bf16x8 pfrag = *(const bf16x8*)(Pw + q15 * SP + kc * 32 + quad * 8);
            const bf16x8 v0f = *(const bf16x8*)(Vt + q15 * SP + kc * 32 + quad * 8);
            const bf16x8 v1f = *(const bf16x8*)(Vt + (q15 + 16) * SP + kc * 32 + quad * 8);
            o0 = __builtin_amdgcn_mfma_f32_16x16x32_bf16(pfrag, v0f, o0, 0, 0, 0);
            o1 = __builtin_amdgcn_mfma_f32_16x16x32_bf16(pfrag, v1f, o1, 0, 0, 0);
        }
        // ---- normalize + scatter to token order ----
        #pragma unroll
        for (int r = 0; r < 4; ++r) {
            const int qr = qbase + quad * 4 + r;
            const float inv = 1.0f / lsum[wave][quad * 4 + r];
            const int pr  = whr * 16 + (qr >> 4);
            const int qqr = wwc * 16 + (qr & 15);
            const long gro = (long)bimg * 16384 + ((pr + 8) & 127) * 128 + ((qqr + 8) & 127);
            bf16* ob = attn_out + gro * 180 + head * 30;
            ob[q15] = __float2bfloat16(o0[r] * inv);
            if (q15 < 14) ob[q15 + 16] = __float2bfloat16(o1[r] * inv);
        }
    }
}

// ---------------- depthwise 5x5 conv + GELU + residual (z = y + gelu(conv)) ---
__global__ __launch_bounds__(256) void dwconv_kernel(const bf16* __restrict__ y,
        const float* __restrict__ dww, const float* __restrict__ dwb,
        bf16* __restrict__ z) {
    __shared__ float wl[25 * 360];   // [tap][ch]
    __shared__ float bl[360];
    const int tid = threadIdx.x;
    for (int e = tid; e < 9000; e += 256) {
        const int ch = e / 25;
        const int tap = e - ch * 25;
        wl[tap * 360 + ch] = dww[e];
    }
    for (int e = tid; e < 360; e += 256) bl[e] = dwb[e];
    __syncthreads();

    const bf162* y2 = (const bf162*)y;
    bf162* z2 = (bf162*)z;
    const int base_t = blockIdx.x * 64;

    #pragma unroll 1
    for (int it = 0; it < 45; ++it) {
        const int item = it * 256 + tid;
        const int tl = item / 180;
        const int pr = item - tl * 180;
        const int t  = base_t + tl;
        const int pw_  = t & 127;
        const int ph   = (t >> 7) & 127;
        const int bimg = t >> 14;
        float s0 = bl[2 * pr], s1 = bl[2 * pr + 1];
        #pragma unroll
        for (int dy = -2; dy <= 2; ++dy) {
            const int hy = ph + dy;
            if (hy < 0 || hy > 127) continue;
            #pragma unroll
            for (int dx = -2; dx <= 2; ++dx) {
                const int wx = pw_ + dx;
                if (wx < 0 || wx > 127) continue;
                const float2 wv = *(const float2*)(wl + ((dy + 2) * 5 + (dx + 2)) * 360 + 2 * pr);
                const float2 yf = __bfloat1622float2(
                    y2[(long)((bimg << 14) + (hy << 7) + wx) * 180 + pr]);
                s0 += yf.x * wv.x;
                s1 += yf.y * wv.y;
            }
        }
        const long oidx = (long)t * 180 + pr;
        const float2 yr = __bfloat1622float2(y2[oidx]);
        bf162 o;
        o.x = __float2bfloat16(yr.x + gelu_f(s0));
        o.y = __float2bfloat16(yr.y + gelu_f(s1));
        z2[oidx] = o;
    }
}

// ---------------- launch --------------------------------------------------------
extern "C" void kernel_launch(void* const* d_in, const int* in_sizes, int n_in,
                              void* d_out, int out_size, void* d_ws, size_t ws_size,
                              hipStream_t stream) {
    const float* x    = (const float*)d_in[0];
    // d_in[1] = attn_mask: unused (mask recomputed analytically in-kernel)
    const int*   rpi  = (const int*)d_in[2];
    const float* n1w  = (const float*)d_in[3];
    const float* n1b  = (const float*)d_in[4];
    const float* wqkv = (const float*)d_in[5];
    const float* bqkv = (const float*)d_in[6];
    const float* rpb  = (const float*)d_in[7];
    const float* pw   = (const float*)d_in[8];
    const float* pb   = (const float*)d_in[9];
    const float* n2w  = (const float*)d_in[10];
    const float* n2b  = (const float*)d_in[11];
    const float* f1w  = (const float*)d_in[12];
    const float* f1b  = (const float*)d_in[13];
    const float* dww  = (const float*)d_in[14];
    const float* dwb  = (const float*)d_in[15];
    const float* f2w  = (const float*)d_in[16];
    const float* f2b  = (const float*)d_in[17];
    float* out = (float*)d_out;

    // workspace: qkvb 141.6MB | abuf 47.2MB | biasN 1.57MB | WT bufs 0.52MB
    const size_t NEED = 540L * TOK * 2 + 180L * TOK * 2 + 393216L * 4 + 259200L * 2;
    if (ws_size < NEED) return;

    bf16* qkvb = (bf16*)d_ws;
    bf16* abuf = qkvb + 540L * TOK;
    bf16* ybuf = qkvb;                    // alias: qkv dead after attention
    bf16* zbuf = qkvb + 360L * TOK;       // spans qkvb tail + abuf (both dead)
    float* biasN = (float*)(qkvb + 720L * TOK);
    bf16* wqkvT = (bf16*)(biasN + 393216);
    bf16* projT = wqkvT + 97200;
    bf16* fc1T  = projT + 32400;
    bf16* fc2T  = fc1T + 64800;

    wtrans_kernel<180, 540><<<380, 256, 0, stream>>>(wqkv, wqkvT);
    wtrans_kernel<180, 180><<<127, 256, 0, stream>>>(pw, projT);
    wtrans_kernel<180, 360><<<254, 256, 0, stream>>>(f1w, fc1T);
    wtrans_kernel<360, 180><<<254, 256, 0, stream>>>(f2w, fc2T);
    biast_kernel<<<256, 256, 0, stream>>>(rpb, rpi, biasN);

    ln_kernel<<<32768, 256, 0, stream>>>(x, n1w, n1b, abuf);
    gemm_mfma<180, 540, 0><<<dim3(2048, 9), 256, 0, stream>>>(abuf, wqkvT, bqkv, nullptr, qkvb);
    attn_mfma<<<3072, 256, 0, stream>>>(qkvb, biasN, abuf);         // abuf := attn_out
    gemm_mfma<180, 180, 2><<<dim3(2048, 3), 256, 0, stream>>>(abuf, projT, pb, x, out);  // out := x2
    ln_kernel<<<32768, 256, 0, stream>>>(out, n2w, n2b, abuf);      // abuf := xn2
    gemm_mfma<180, 360, 1><<<dim3(2048, 6), 256, 0, stream>>>(abuf, fc1T, f1b, nullptr, ybuf);
    dwconv_kernel<<<2048, 256, 0, stream>>>(ybuf, dww, dwb, zbuf);
    gemm_mfma<360, 180, 3><<<dim3(2048, 3), 256, 0, stream>>>(zbuf, fc2T, f2b, out, out);
}